// Round 5
// baseline (491.018 us; speedup 1.0000x reference)
//
#include <hip/hip_runtime.h>

// B=4, T=4096, D=A=1024.  All-MFMA bf16 pipeline.
// R15: 2-phase double-buffered K-loops (catalog T3-minimum) at BK=32, same
//   LDS footprint as R14 (48KB/32KB => occupancy preserved: 3 / 4-5 blocks/CU).
//   Evidence (R14 counters + corrected per-SIMD MFMA rate ~19.4cyc): s_gemm_v
//   3430 cyc/block-K-tile vs MFMA 1242 + LDS ~1000; LDS only ~30% busy,
//   MfmaUtil 32% => the ~2200-cyc gap is the load-latency drain at the
//   barrier (loads issued right before the sync that drains them).  Fix:
//   issue next-tile global_load_lds BEFORE current-tile ds_read+MFMA; ONE
//   __syncthreads per K-step (implicit vmcnt(0) lands after the MFMA work).
//   Barrier count unchanged (32x1 vs 16x2).  Numerics identical (old h=0/1
//   pair == two sequential K=32 steps in the same order).
// Rotation swizzle at 4 granules/row (conflict-free by the R12 argument):
//   logical granule g (8 elems) of tile-row R stored at phys (g+R)&3 within
//   the 32-elem row.  Reads: co = ((qq+r)&3)<<3.  Staging pre-permutes the
//   GLOBAL source granule ((tid&3 - tid>>2)&3); DMA dest stays linear
//   lane*16B (m104); 4 lanes/row = 64B contiguous segments (coalesced).
// R14 mappings kept: o_gemm balanced quads (66 K-units per CU-slot),
//   s_gemm_v flat active-only triangular grid, proj_qk XCD-swizzled.
// Packed S: row-block y128 at elem offset y128(y128+1)/2*16384, ld (y128+1)*128.
// ws: Q 32MB | K 32MB | Vt 32MB | S G*17.3MB   (G from ws_size)
// d_out (64MB) doubles as Xb(32MB)+Wb(6MB) scratch during projection.

#define T_SEQ 4096
#define DA    1024
#define BATCH 4
#define M_TOT (BATCH * T_SEQ)            // 16384
#define SB_ELEMS 8650752                  // 528 tri-blocks * 16384 elems

typedef float  f32x4  __attribute__((ext_vector_type(4)));
typedef short  bf16x8 __attribute__((ext_vector_type(8)));

static __device__ __forceinline__ unsigned short f2bf(float f) {
    unsigned u = __builtin_bit_cast(unsigned, f);
    u += 0x7FFFu + ((u >> 16) & 1u);      // RNE
    return (unsigned short)(u >> 16);
}
static __device__ __forceinline__ unsigned pack2(float a, float b) {
    return (unsigned)f2bf(a) | ((unsigned)f2bf(b) << 16);
}
static __device__ __forceinline__ float bflo(unsigned u) {
    return __builtin_bit_cast(float, u << 16);
}
static __device__ __forceinline__ float bfhi(unsigned u) {
    return __builtin_bit_cast(float, u & 0xFFFF0000u);
}

// async global->LDS, 16 B per lane; LDS dest = wave-uniform base + lane*16
#define GLOAD_LDS16(g, l)                                                   \
    __builtin_amdgcn_global_load_lds(                                       \
        (const __attribute__((address_space(1))) void*)(g),                 \
        (__attribute__((address_space(3))) void*)(l), 16, 0, 0)

// ---------------------------------------------------------------------------
// MFMA step for one K=32 sub-tile.  Row stride 32 elems; granule-rotated.
// ---------------------------------------------------------------------------
static __device__ __forceinline__ void mfma_step32(
    const unsigned short* __restrict__ Xs, const unsigned short* __restrict__ Ws,
    int wm, int wn, int r, int swz, f32x4 acc[4][4])
{
    bf16x8 a[4], b[4];
    #pragma unroll
    for (int i = 0; i < 4; ++i)
        a[i] = *(const bf16x8*)&Xs[(wm * 64 + i * 16 + r) * 32 + swz];
    #pragma unroll
    for (int j = 0; j < 4; ++j)
        b[j] = *(const bf16x8*)&Ws[(wn * 64 + j * 16 + r) * 32 + swz];
    #pragma unroll
    for (int i = 0; i < 4; ++i)
        #pragma unroll
        for (int j = 0; j < 4; ++j)
            acc[i][j] = __builtin_amdgcn_mfma_f32_16x16x32_bf16(
                a[i], b[j], acc[i][j], 0, 0, 0);
}

// ---------------------------------------------------------------------------
// 256-thread dbuf K-loop: 128x32 A + 128x32 B per step (o_gemm).
// Xs/Ws each 8192 shorts = 2 buffers x 128x32.
// ---------------------------------------------------------------------------
static __device__ __forceinline__ void k_loop_256(
    const unsigned short* __restrict__ A, int lda,
    const unsigned short* __restrict__ B, int ldb,
    int m0, int n0, int K,
    unsigned short* __restrict__ Xs, unsigned short* __restrict__ Ws,
    int tid, int wm, int wn, int r, int swz, f32x4 acc[4][4])
{
    const int srow = tid >> 2;                              // 0..63
    const int scg  = (((tid & 3) - srow) & 3) * 8;
    const unsigned short* ga = A + (size_t)(m0 + srow) * lda + scg;
    const unsigned short* gb = B + (size_t)(n0 + srow) * ldb + scg;
    const size_t a64 = (size_t)64 * lda;
    const size_t b64 = (size_t)64 * ldb;

    GLOAD_LDS16(ga,       Xs + tid * 8);
    GLOAD_LDS16(ga + a64, Xs + 2048 + tid * 8);
    GLOAD_LDS16(gb,       Ws + tid * 8);
    GLOAD_LDS16(gb + b64, Ws + 2048 + tid * 8);
    __syncthreads();

    int cur = 0;
    for (int k0 = 0; k0 < K; k0 += 32) {
        const int nxt = cur ^ 1;
        if (k0 + 32 < K) {
            const unsigned short* pa = ga + k0 + 32;
            const unsigned short* pb = gb + k0 + 32;
            GLOAD_LDS16(pa,       Xs + nxt * 4096 + tid * 8);
            GLOAD_LDS16(pa + a64, Xs + nxt * 4096 + 2048 + tid * 8);
            GLOAD_LDS16(pb,       Ws + nxt * 4096 + tid * 8);
            GLOAD_LDS16(pb + b64, Ws + nxt * 4096 + 2048 + tid * 8);
        }
        mfma_step32(Xs + cur * 4096, Ws + cur * 4096, wm, wn, r, swz, acc);
        __syncthreads();
        cur = nxt;
    }
}

// ---------------------------------------------------------------------------
// 512-thread dbuf K-loop: 256x32 A + 128x32 B per step (proj/s_gemm_v).
// Xs 16384 shorts = 2 x 256x32; Ws 8192 shorts = 2 x 128x32.
// ---------------------------------------------------------------------------
static __device__ __forceinline__ void k_loop_512(
    const unsigned short* __restrict__ A, int lda,
    const unsigned short* __restrict__ B, int ldb,
    int m0, int n0, int K,
    unsigned short* __restrict__ Xs, unsigned short* __restrict__ Ws,
    int tid, int wm, int wn, int r, int swz, f32x4 acc[4][4])
{
    const int srow = tid >> 2;                              // 0..127
    const int scg  = (((tid & 3) - srow) & 3) * 8;
    const unsigned short* ga = A + (size_t)(m0 + srow) * lda + scg;
    const unsigned short* gb = B + (size_t)(n0 + srow) * ldb + scg;
    const size_t a128 = (size_t)128 * lda;

    GLOAD_LDS16(ga,        Xs + tid * 8);
    GLOAD_LDS16(ga + a128, Xs + 4096 + tid * 8);
    GLOAD_LDS16(gb,        Ws + tid * 8);
    __syncthreads();

    int cur = 0;
    for (int k0 = 0; k0 < K; k0 += 32) {
        const int nxt = cur ^ 1;
        if (k0 + 32 < K) {
            const unsigned short* pa = ga + k0 + 32;
            GLOAD_LDS16(pa,        Xs + nxt * 8192 + tid * 8);
            GLOAD_LDS16(pa + a128, Xs + nxt * 8192 + 4096 + tid * 8);
            GLOAD_LDS16(gb + k0 + 32, Ws + nxt * 4096 + tid * 8);
        }
        mfma_step32(Xs + cur * 8192, Ws + cur * 4096, wm, wn, r, swz, acc);
        __syncthreads();
        cur = nxt;
    }
}

#define GEMM_VARS                                                            \
    const int tid  = threadIdx.x;                                            \
    const int wave = tid >> 6;                                               \
    const int lane = tid & 63;                                               \
    const int wm   = wave >> 1;                                              \
    const int wn   = wave & 1;                                               \
    const int qq   = lane >> 4;                                              \
    const int r    = lane & 15;                                              \
    const int swz  = ((qq + r) & 3) << 3;                                    \
    f32x4 acc[4][4];                                                         \
    _Pragma("unroll")                                                        \
    for (int i = 0; i < 4; ++i)                                              \
        _Pragma("unroll")                                                    \
        for (int j = 0; j < 4; ++j)                                          \
            acc[i][j] = f32x4{0.f, 0.f, 0.f, 0.f};

#define GEMM_PROLOGUE_256                                                    \
    __shared__ unsigned short Xs[8192];                                      \
    __shared__ unsigned short Ws[8192];                                      \
    GEMM_VARS

#define GEMM_PROLOGUE_512                                                    \
    __shared__ unsigned short Xs[16384];                                     \
    __shared__ unsigned short Ws[8192];                                      \
    GEMM_VARS

// C/D layout: col = lane&15, row = (lane>>4)*4 + reg   (row within wave tile)
#define EPILOGUE_LOOP(BODY)                                                  \
    _Pragma("unroll")                                                        \
    for (int i = 0; i < 4; ++i)                                              \
        _Pragma("unroll")                                                    \
        for (int j = 0; j < 4; ++j)                                          \
            _Pragma("unroll")                                                \
            for (int rr = 0; rr < 4; ++rr) {                                 \
                const int row = wm * 64 + i * 16 + qq * 4 + rr;              \
                const int col = wn * 64 + j * 16 + r;                        \
                const float val = acc[i][j][rr];                             \
                BODY                                                         \
            }

// transposed V epilogue: rows rg0..rg0+3 are consecutive t -> one ushort4
#define EPILOGUE_VT(VT, M0, NC)                                              \
    _Pragma("unroll")                                                        \
    for (int i = 0; i < 4; ++i)                                              \
        _Pragma("unroll")                                                    \
        for (int j = 0; j < 4; ++j) {                                        \
            const int rg0 = (M0) + wm * 64 + i * 16 + qq * 4;                \
            const int col = wn * 64 + j * 16 + r;                            \
            const int bb  = rg0 >> 12;                                       \
            const int tt  = rg0 & 4095;                                      \
            ushort4 pkv;                                                     \
            pkv.x = f2bf(acc[i][j][0]); pkv.y = f2bf(acc[i][j][1]);          \
            pkv.z = f2bf(acc[i][j][2]); pkv.w = f2bf(acc[i][j][3]);          \
            *(ushort4*)&(VT)[((size_t)bb << 22) +                            \
                             (size_t)((NC) + col) * 4096 + tt] = pkv;        \
        }

// ---------------------------------------------------------------------------
// fp32 -> bf16 conversion. Blocks 0..8191: X. Blocks 8192..9727: Wq|Wk|Wv.
// ---------------------------------------------------------------------------
__global__ __launch_bounds__(256) void to_bf16_all(
    const float* __restrict__ X, const float* __restrict__ Wq,
    const float* __restrict__ Wk, const float* __restrict__ Wv,
    unsigned short* __restrict__ Xb, unsigned short* __restrict__ Wb)
{
    const int bx = blockIdx.x;
    const float* src;
    unsigned short* dst;
    size_t off;
    if (bx < 8192) {
        src = X; dst = Xb; off = (size_t)bx * 2048;
    } else {
        const int s   = bx - 8192;
        const int seg = s >> 9;
        src = (seg == 0) ? Wq : (seg == 1) ? Wk : Wv;
        dst = Wb + (size_t)seg * (DA * DA);
        off = (size_t)(s & 511) * 2048;
    }
    const size_t i = off + (size_t)threadIdx.x * 8;
    const float4 v0 = *(const float4*)(src + i);
    const float4 v1 = *(const float4*)(src + i + 4);
    uint4 pk;
    pk.x = pack2(v0.x, v0.y); pk.y = pack2(v0.z, v0.w);
    pk.z = pack2(v1.x, v1.y); pk.w = pack2(v1.z, v1.w);
    *(uint4*)(dst + i) = pk;
}

// ---------------------------------------------------------------------------
// Q,K projections, 256x128 tiles. Wb = [3*1024][1024]. 1024 blocks,
// XCD-swizzled: xcd owns mt band [xcd*8, xcd*8+8), n fastest.
// ---------------------------------------------------------------------------
__global__ __launch_bounds__(512) void proj_qk(
    const unsigned short* __restrict__ Xb, const unsigned short* __restrict__ Wb,
    unsigned short* __restrict__ qb, unsigned short* __restrict__ kb)
{
    const int li   = blockIdx.x;
    const int xcd  = li & 7;
    const int slot = li >> 3;            // 0..127
    const int mt   = xcd * 8 + (slot >> 4);
    const int nt   = slot & 15;          // 0..15 across Wq|Wk
    const int m0   = mt * 256;

    GEMM_PROLOGUE_512
    k_loop_512(Xb, DA, Wb, DA, m0, nt * 128, DA, Xs, Ws,
               tid, wm, wn, r, swz, acc);

    unsigned short* Y = (nt >> 3) ? kb : qb;
    const int nc = (nt & 7) * 128;
    EPILOGUE_LOOP({
        Y[(size_t)(m0 + row) * DA + (nc + col)] = f2bf(val);
    })
}

// ---------------------------------------------------------------------------
// Fallback V projection (only if workspace forces G<4). 512 blocks, 256x128.
// ---------------------------------------------------------------------------
__global__ __launch_bounds__(512) void proj_v(
    const unsigned short* __restrict__ Xb, const unsigned short* __restrict__ Wb,
    unsigned short* __restrict__ vt)
{
    const int li = blockIdx.x;           // 0..511
    const int m0 = (li >> 3) * 256;
    const int n0 = (li & 7) * 128;
    GEMM_PROLOGUE_512
    k_loop_512(Xb, DA, Wb + (size_t)2048 * DA, DA, m0, n0, DA, Xs, Ws,
               tid, wm, wn, r, swz, acc);
    EPILOGUE_VT(vt, m0, n0)
}

// ---------------------------------------------------------------------------
// S = Q.K^T / 32 (lower-tri, packed) with V tiles on dead upper slots.
// Flat active-only grid (272 + vPerZ, G), 512 threads, 256x128 tiles.
// t < 272: S tile; triangular decode yr(yr+1) <= t < (yr+1)(yr+2),
//   x = t - yr(yr+1).  Rows span packed blocks 2yr, 2yr+1 (different ld)
//   -> per-element y128/ld; col guard drops dead half of boundary tile.
// t >= 272: V tile vid = bz*vPerZ + (t-272).
// ---------------------------------------------------------------------------
__global__ __launch_bounds__(512) void s_gemm_v(
    const unsigned short* __restrict__ qb, const unsigned short* __restrict__ kb,
    const unsigned short* __restrict__ Xb, const unsigned short* __restrict__ Wb,
    unsigned short* __restrict__ sbuf, unsigned short* __restrict__ vt,
    int bbase, int vPerZ)
{
    const int t  = blockIdx.x;
    const int bz = blockIdx.y;
    const bool isS = (t < 272);

    const unsigned short *Am, *Bm;
    int m0, n0;
    if (isS) {
        int yr = (int)((__fsqrt_rn(4.f * (float)t + 1.f) - 1.f) * 0.5f);
        while ((yr + 1) * (yr + 2) <= t) ++yr;      // exact fixup
        while (yr * (yr + 1) > t) --yr;
        const int x = t - yr * (yr + 1);
        const int b = bbase + bz;
        Am = qb + (size_t)b * T_SEQ * DA;
        Bm = kb + (size_t)b * T_SEQ * DA;
        m0 = yr * 256;
        n0 = x * 128;
    } else {
        const int vid = bz * vPerZ + (t - 272);      // 0..511
        Am = Xb;
        Bm = Wb + (size_t)2048 * DA;
        m0 = (vid >> 3) * 256;
        n0 = (vid & 7) * 128;
    }

    GEMM_PROLOGUE_512
    k_loop_512(Am, DA, Bm, DA, m0, n0, DA, Xs, Ws,
               tid, wm, wn, r, swz, acc);

    if (isS) {
        unsigned short* Sz = sbuf + (size_t)bz * SB_ELEMS;
        EPILOGUE_LOOP({
            const int grow = m0 + row;
            const int y128 = grow >> 7;
            const int ld   = (y128 + 1) * 128;
            const int colg = n0 + col;
            if (colg < ld)
                Sz[(size_t)(y128 * (y128 + 1) / 2) * 16384
                   + (size_t)(grow & 127) * ld + colg] = f2bf(val * 0.03125f);
        })
    } else {
        EPILOGUE_VT(vt, m0, n0)
    }
}

// ---------------------------------------------------------------------------
// Row softmax on packed S. grid (4096, G); big rows first.
// ---------------------------------------------------------------------------
__global__ __launch_bounds__(256) void softmax_rows(unsigned short* __restrict__ sbuf)
{
    __shared__ float row[4096];
    __shared__ float red[4];
    const int q   = 4095 - (int)blockIdx.x;
    const int n   = q + 1;
    const int tid = threadIdx.x;
    const int y   = q >> 7;
    const int ld  = (y + 1) * 128;
    unsigned short* rp = sbuf + (size_t)blockIdx.y * SB_ELEMS
                       + (size_t)(y * (y + 1) / 2) * 16384
                       + (size_t)(q & 127) * ld;
    const int n8 = n & ~7;

    for (int i0 = tid * 8; i0 < n8; i0 += 2048) {
        const uint4 v = *(const uint4*)(rp + i0);
        *(float4*)&row[i0]     = make_float4(bflo(v.x), bfhi(v.x), bflo(v.y), bfhi(v.y));
        *(float4*)&row[i0 + 4] = make_float4(bflo(v.z), bfhi(v.z), bflo(v.w), bfhi(v.w));
    }
    for (int i = n8 + tid; i < n; i += 256)
        row[i] = __builtin_bit_cast(float, (unsigned)rp[i] << 16);
    __syncthreads();

    float m = -1e30f;
    for (int i = tid; i < n; i += 256) m = fmaxf(m, row[i]);
    #pragma unroll
    for (int off = 32; off >= 1; off >>= 1) m = fmaxf(m, __shfl_xor(m, off, 64));
    if ((tid & 63) == 0) red[tid >> 6] = m;
    __syncthreads();
    m = fmaxf(fmaxf(red[0], red[1]), fmaxf(red[2], red[3]));
    __syncthreads();

    float s = 0.f;
    for (int i = tid; i < n; i += 256) {
        const float e = __expf(row[i] - m);
        row[i] = e;
        s += e;
    }
    #pragma unroll
    for (int off = 32; off >= 1; off >>= 1) s += __shfl_xor(s, off, 64);
    if ((tid & 63) == 0) red[tid >> 6] = s;
    __syncthreads();
    s = red[0] + red[1] + red[2] + red[3];
    const float inv = 1.f / s;

    for (int i0 = tid * 8; i0 < n8; i0 += 2048) {
        const float4 f0 = *(const float4*)&row[i0];
        const float4 f1 = *(const float4*)&row[i0 + 4];
        uint4 pk;
        pk.x = pack2(f0.x * inv, f0.y * inv);
        pk.y = pack2(f0.z * inv, f0.w * inv);
        pk.z = pack2(f1.x * inv, f1.y * inv);
        pk.w = pack2(f1.z * inv, f1.w * inv);
        *(uint4*)(rp + i0) = pk;
    }
    for (int i = n8 + tid; i < ld; i += 256)
        rp[i] = (i < n) ? f2bf(row[i] * inv) : (unsigned short)0;
}

// ---------------------------------------------------------------------------
// out = P.Vt^T, K = (y+1)*128. grid (8, 32*G), 256 threads, 128x128.
// Balanced mapping (G==4): w = blockIdx.y; s = w&31 (CU slot), r = w>>5,
//   i = s&7, z = s>>3; y = {31-i, 16+i, 15-i, i}[r].  Per-CU K-units = 66
//   for every slot; (y,z) bijective; big-y member dispatched first.
// ---------------------------------------------------------------------------
__global__ __launch_bounds__(256) void o_gemm(
    const unsigned short* __restrict__ sbuf, const unsigned short* __restrict__ vt,
    float* __restrict__ out, int bbase)
{
    const int w = blockIdx.y;
    int y, z;
    if (gridDim.y == 128) {
        const int s  = w & 31;
        const int rr = w >> 5;
        const int i  = s & 7;
        z = s >> 3;
        y = (rr == 0) ? (31 - i) : (rr == 1) ? (16 + i)
          : (rr == 2) ? (15 - i) : i;
    } else {
        const int gy = w & 31;
        z = w >> 5;
        y = (gy & 1) ? (gy >> 1) : (31 - (gy >> 1));
    }
    const int b  = bbase + z;
    const int K_len = (y + 1) * 128;
    const unsigned short* A  = sbuf + (size_t)z * SB_ELEMS
                             + (size_t)(y * (y + 1) / 2) * 16384;
    const unsigned short* Bv = vt + (size_t)b * T_SEQ * DA;   // [1024][4096]
    const int n0 = blockIdx.x * 128;

    GEMM_PROLOGUE_256
    k_loop_256(A, K_len, Bv, T_SEQ, 0, n0, K_len, Xs, Ws,
               tid, wm, wn, r, swz, acc);

    float* outb = out + (size_t)b * T_SEQ * DA + (size_t)y * 128 * DA;
    EPILOGUE_LOOP({
        outb[(size_t)row * DA + (n0 + col)] = rintf(val * 1e4f) * 1e-4f;
    })
}

// ---------------------------------------------------------------------------
extern "C" void kernel_launch(void* const* d_in, const int* in_sizes, int n_in,
                              void* d_out, int out_size, void* d_ws, size_t ws_size,
                              hipStream_t stream)
{
    const float* X  = (const float*)d_in[0];
    const float* Wq = (const float*)d_in[1];
    const float* Wk = (const float*)d_in[2];
    const float* Wv = (const float*)d_in[3];
    float* out = (float*)d_out;

    unsigned short* qb   = (unsigned short*)d_ws;          // [16384,1024]
    unsigned short* kb   = qb + (size_t)M_TOT * DA;
    unsigned short* vt   = kb + (size_t)M_TOT * DA;        // [4][1024][4096]
    unsigned short* sbuf = vt + (size_t)M_TOT * DA;        // G * SB_ELEMS

    // bf16 copies of X / W live in d_out (64 MB), dead until o_gemm writes.
    unsigned short* Xb = (unsigned short*)d_out;           // 32 MB
    unsigned short* Wb = Xb + (size_t)M_TOT * DA;          // 6 MB ([3*1024][1024])

    const size_t fixed = (size_t)3 * M_TOT * DA * 2;
    int G = 1;
    if (ws_size >= fixed + (size_t)4 * SB_ELEMS * 2) G = 4;
    else if (ws_size >= fixed + (size_t)2 * SB_ELEMS * 2) G = 2;

    to_bf16_all<<<9728, 256, 0, stream>>>(X, Wq, Wk, Wv, Xb, Wb);
    proj_qk<<<1024, 512, 0, stream>>>(Xb, Wb, qb, kb);
    if (G < 4)
        proj_v<<<512, 512, 0, stream>>>(Xb, Wb, vt);

    for (int b0 = 0; b0 < BATCH; b0 += G) {
        const int vPerZ = (G == 4) ? 128 : 0;   // V fused only in the G=4 path
        s_gemm_v<<<dim3(272 + vPerZ, G), 512, 0, stream>>>(
            qb, kb, Xb, Wb, sbuf, vt, b0, vPerZ);
        softmax_rows<<<dim3(4096, G), 256, 0, stream>>>(sbuf);
        o_gemm<<<dim3(8, 32 * G), 256, 0, stream>>>(sbuf, vt, out, b0);
    }
}